// Round 11
// baseline (680.281 us; speedup 1.0000x reference)
//
#include <hip/hip_runtime.h>

// LSTM enc(20, in=2) + dec(30, in=h) fused, HID=64, f32 I/O.
// Gates-transposed MFMA recurrence, v_mfma_f32_16x16x32_f16 (K=32).
//   D[n][m] = sum_k W[n][k] h[m][k]; C/D: col=l&15, row=4*(l>>4)+r.
// k-relabeling f(q,tg,e) = 32q+8tg+e on BOTH operands (bijection -> D
// unchanged): A-frag q = 8 contiguous W[n][32q+8tg..+7], B-frag q =
// h[32q+8tg..+7] from identity-layout LDS.  Wave w owns hidden
// [16w,16w+16); h exchanged via dbuf XOR-swizzled Hh, 1 barrier/step.
// x-projection = 3rd MFMA (q2): A=[Wa,Wb,bias]*gsc (tg0), B=[xa,xb,1]f16.
// TWO batch tiles/block (32 batch), (256,3), W frags in LDS (R13).
//
// R8/R9: f16 scheme: 16 gate-MFMAs/step; absmax floor 2.4e-4.
// R10-R12: allocator clamp = 2x-unified split: (256,2)->108, (256,3)->84,
//   (256,4)->64 arch VGPRs; spills catastrophic.
// R13: W frags + x-proj evicted to LDS/MFMA: no spill, VGPR 68, wall 432.
// R14 FAILED: 1-tile (256,4): occ 45% but VALUBusy stuck 71; MODEL:
//   VALUBusy+MfmaUtil = 93-97% everywhere -> ONE shared SIMD issue
//   budget; only lever is fewer issue cycles.  Inventory/wave-step:
//   trans 896 (56x16cy) + full ~130 + MFMA ~396 = 1425/1470.
// R15 FAILED correctness (9.1e-2): poly exp2 via MAGIC-ADD round
//   ((x+M)-M).  Diagnosis: a ~4e-5-accurate exp2 cannot give 9e-2
//   (f16-h noise 4.9e-4 yields only 2.4e-4 final) -> exp2p returned
//   WRONG values.  Prime suspect: value-unsafe FP folding collapses
//   x-((x+M)-M) to 0 -> exp2 degenerates to 2^round(x) step function
//   -> sigmoid err ~0.1 -> matches 9e-2.  All prior numerics used
//   opaque intrinsics/bit-casts; the magic-add was the first foldable
//   idiom.  rcp_pair algebra verified safe (overflow needs sum|gates|
//   ~89 across a row pair -- impossible).
// R16 (this round): same optimization, fold-proof formulation:
//   round = rintf (v_rndne_f32, opaque; x-rintf(x) has no algebraic
//   identity), scale = ldexpf (v_ldexp_f32, full-rate; no bit-splice,
//   no negative-shift), deg-5 Taylor (rel err 2.4e-6, 20x margin).
//   Keep rcp_pair.  ~1470 -> ~1180 cy/wave-step.  Predict rocprof
//   490 -> 400-425, VALU ~65, Mfma ~30 (sum ~96), absmax <= 5e-4.
//   Fallback if absmax fails again: hw exp2 + rcp_pair only.

#define LOG2E 1.44269504088896340736f
#define TWO_LOG2E 2.88539008177792681472f

typedef __attribute__((ext_vector_type(4))) short short4v;
typedef __attribute__((ext_vector_type(4))) float float4v;
typedef __attribute__((ext_vector_type(4))) unsigned int uint4v;
typedef _Float16 __attribute__((ext_vector_type(8))) half8v;

#if defined(__HIP_DEVICE_COMPILE__)
#define MFMAH(a, b, c) __builtin_amdgcn_mfma_f32_16x16x32_f16((a), (b), (c), 0, 0, 0)
#else
#define MFMAH(a, b, c) (c)
#endif

// 2^x, fold-proof: rndne + deg-5 Taylor on [-0.5,0.5] + ldexp.
// Valid for |x| <= ~1e6; rel err ~2.4e-6.
__device__ __forceinline__ float4v exp2p(float4v x) {
  float4v rn;
#pragma unroll
  for (int j = 0; j < 4; ++j) rn[j] = rintf(x[j]);   // v_rndne_f32
  float4v f = x - rn;                                // f in [-0.5, 0.5]
  float4v p = f * 0.0013333558f + 0.0096181291f;
  p = p * f + 0.0555041087f;
  p = p * f + 0.2402265070f;
  p = p * f + 0.6931471806f;
  p = p * f + 1.0f;
  float4v r;
#pragma unroll
  for (int j = 0; j < 4; ++j) r[j] = ldexpf(p[j], (int)rn[j]);  // v_ldexp
  return r;
}

// 1/d elementwise with rcps PAIRED across (0,1) and (2,3):
// r01 = rcp(d0*d1); 1/d0 = d1*r01, 1/d1 = d0*r01.  2 trans instead of 4.
__device__ __forceinline__ float4v rcp_pair(float4v d) {
  float r01 = __builtin_amdgcn_rcpf(d[0] * d[1]);
  float r23 = __builtin_amdgcn_rcpf(d[2] * d[3]);
  float4v r;
  r[0] = d[1] * r01;
  r[1] = d[0] * r01;
  r[2] = d[3] * r23;
  r[3] = d[2] * r23;
  return r;
}

// Fused LSTM cell update on 4 rows (pk-f32).  a[0..3] = gates i,f,g,o
// PRE-SCALED (i,f,o by -log2e; g by 2log2e).  c holds 2log2e*cell.
__device__ __forceinline__ void cellact(const float4v* a, float4v& c,
                                        short4v& hh) {
  const float4v one = {1.f, 1.f, 1.f, 1.f};
  const float4v clo = {-36.f, -36.f, -36.f, -36.f};
  const float4v chi = {36.f, 36.f, 36.f, 36.f};
  float4v Ei = exp2p(a[0]);                     // e^{-i}
  float4v Ef = exp2p(a[1]);                     // e^{-f}
  float4v Eg = exp2p(a[2]);                     // e^{2g}
  float4v Eo = exp2p(a[3]);                     // e^{-o}
  float4v t3 = one + Ef;
  float4v P  = (one + Ei) * (one + Eg);
  float4v t4s = Eg * TWO_LOG2E - TWO_LOG2E;     // 2log2e*(Eg-1)
  float4v num = c * P + t4s * t3;
  float4v cs = num * rcp_pair(P * t3);          // 2log2e * c_new
  c = cs;
  float4v cl = __builtin_elementwise_min(__builtin_elementwise_max(cs, clo), chi);
  float4v Ec = exp2p(cl);
  float4v h = (Ec - one) * rcp_pair((one + Ec) * (one + Eo));
#pragma unroll
  for (int r = 0; r < 4; ++r) {
    _Float16 hf = (_Float16)h[r];               // v_cvt_f16_f32 (RNE)
    hh[r] = (short)__builtin_bit_cast(unsigned short, hf);
  }
}

__global__ __launch_bounds__(256, 3) void lstm_fused(
    const float* __restrict__ x,     // [B][20][2]
    const float* __restrict__ eWih,  // [256][2]
    const float* __restrict__ eWhh,  // [256][64]
    const float* __restrict__ ebih,  // [256]
    const float* __restrict__ ebhh,  // [256]
    const float* __restrict__ dWih,  // [256][64]
    const float* __restrict__ dWhh,  // [256][64]
    const float* __restrict__ dbih,  // [256]
    const float* __restrict__ dbhh,  // [256]
    const float* __restrict__ linW,  // [2][64]
    const float* __restrict__ linb,  // [2]
    float* __restrict__ out,         // [B][30][2]
    int B) {
  const int tid = threadIdx.x;
  const int w   = tid >> 6;    // wave: hidden block [16w, 16w+16)
  const int l   = tid & 63;
  const int m   = l & 15;      // batch col within tile
  const int tg  = l >> 4;
  const int msk = m & 14;
  const int wslot = (((w << 2) | tg) ^ msk) << 2;   // halfword off, b64 write
  const int bg  = blockIdx.x * 32;

  __shared__ __align__(16) unsigned short WL[10][256][8];  // W/LA frags, f16
  __shared__ __align__(16) unsigned short Hh[2][32][64];   // h, f16 bits
  __shared__ unsigned int Xs16[32][21];                    // packed f16 x

  const half8v hz8 = {0, 0, 0, 0, 0, 0, 0, 0};
  const float4v zf = {0.f, 0.f, 0.f, 0.f};

  // ---- stage x as packed f16 pairs: Xs16[mm][st] = (xb|xa) ----
  {
    const size_t xoff = (size_t)blockIdx.x * 1280;
    for (int i = tid; i < 640; i += 256) {
      int mm = i / 20, st = i - mm * 20;
      size_t g = xoff + (size_t)mm * 40 + st * 2;
      float xa = 0.f, xb = 0.f;
      if (g + 1 < (size_t)B * 40) { xa = x[g]; xb = x[g + 1]; }
      unsigned ua = __builtin_bit_cast(unsigned short, (_Float16)xa);
      unsigned ub = __builtin_bit_cast(unsigned short, (_Float16)xb);
      Xs16[mm][st] = (ub << 16) | ua;
    }
  }

  // ---- encoder weights: Whh frags -> WL[0..7]; x/bias frag q2 in regs ----
  half8v eA2[4];
#pragma unroll
  for (int gi = 0; gi < 4; ++gi) {
    const float gsc = (gi == 2) ? TWO_LOG2E : -LOG2E;
    const int nA = m + 16 * (4 * gi + w);
#pragma unroll
    for (int q = 0; q < 2; ++q) {
      const float* wp = &eWhh[nA * 64 + 32 * q + 8 * tg];
      float4v w0 = *(const float4v*)wp;
      float4v w1 = *(const float4v*)(wp + 4);
      half8v hi;
#pragma unroll
      for (int e = 0; e < 4; ++e) {
        hi[e]     = (_Float16)(w0[e] * gsc);
        hi[4 + e] = (_Float16)(w1[e] * gsc);
      }
      *(half8v*)&WL[gi * 2 + q][tid][0] = hi;
    }
    half8v a2 = hz8;
    if (tg == 0) {
      a2[0] = (_Float16)(eWih[nA * 2 + 0] * gsc);
      a2[1] = (_Float16)(eWih[nA * 2 + 1] * gsc);
      a2[2] = (_Float16)((ebih[nA] + ebhh[nA]) * gsc);
    }
    eA2[gi] = a2;
  }

  __syncthreads();   // Xs16 + WL ready

  float4v c0 = {0.f, 0.f, 0.f, 0.f}, c1 = {0.f, 0.f, 0.f, 0.f};
  half8v b0[2] = {hz8, hz8}, b1[2] = {hz8, hz8};
  int p = 0;

  // ---- encoder: 20 steps (tile-sequential; frags re-read per tile) ----
#pragma unroll 1
  for (int st = 0; st < 20; ++st) {
    short4v hh0, hh1;
    {
      uint4v t; t[0] = Xs16[m][st]; t[1] = 0x3C00u; t[2] = 0u; t[3] = 0u;
      half8v bq2 = (tg == 0) ? __builtin_bit_cast(half8v, t) : hz8;
      float4v a0[4];
#pragma unroll
      for (int gi = 0; gi < 4; ++gi) {
        half8v f0 = *(const half8v*)&WL[gi * 2 + 0][tid][0];
        half8v f1 = *(const half8v*)&WL[gi * 2 + 1][tid][0];
        float4v a = MFMAH(eA2[gi], bq2, zf);
        a = MFMAH(f0, b0[0], a);
        a0[gi] = MFMAH(f1, b0[1], a);
      }
      cellact(a0, c0, hh0);
    }
    {
      uint4v t; t[0] = Xs16[m + 16][st]; t[1] = 0x3C00u; t[2] = 0u; t[3] = 0u;
      half8v bq2 = (tg == 0) ? __builtin_bit_cast(half8v, t) : hz8;
      float4v a1[4];
#pragma unroll
      for (int gi = 0; gi < 4; ++gi) {
        half8v f0 = *(const half8v*)&WL[gi * 2 + 0][tid][0];
        half8v f1 = *(const half8v*)&WL[gi * 2 + 1][tid][0];
        float4v a = MFMAH(eA2[gi], bq2, zf);
        a = MFMAH(f0, b1[0], a);
        a1[gi] = MFMAH(f1, b1[1], a);
      }
      cellact(a1, c1, hh1);
    }
    *(short4v*)&Hh[p][m][wslot]      = hh0;
    *(short4v*)&Hh[p][m + 16][wslot] = hh1;
    __syncthreads();
#pragma unroll
    for (int q = 0; q < 2; ++q) {
      const int rs = (((8 * q) | (2 * tg)) ^ msk) << 2;
      b0[q] = *(const half8v*)&Hh[p][m][rs];
      b1[q] = *(const half8v*)&Hh[p][m + 16][rs];
    }
    p ^= 1;
  }

  // ---- transition: repack WL with decoder Wsum + LA; dbsv in regs ----
  // (legal: every encoder WL read precedes the step-19 barrier)
  float4v dbsv[4];
#pragma unroll
  for (int gi = 0; gi < 4; ++gi) {
    const float gsc = (gi == 2) ? TWO_LOG2E : -LOG2E;
    const int nA = m + 16 * (4 * gi + w);
#pragma unroll
    for (int q = 0; q < 2; ++q) {
      const float* wpa = &dWih[nA * 64 + 32 * q + 8 * tg];
      const float* wpb = &dWhh[nA * 64 + 32 * q + 8 * tg];
      float4v a0v = *(const float4v*)wpa;
      float4v a1v = *(const float4v*)(wpa + 4);
      float4v b0v = *(const float4v*)wpb;
      float4v b1v = *(const float4v*)(wpb + 4);
      half8v hi;
#pragma unroll
      for (int e = 0; e < 4; ++e) {
        hi[e]     = (_Float16)((a0v[e] + b0v[e]) * gsc);
        hi[4 + e] = (_Float16)((a1v[e] + b1v[e]) * gsc);
      }
      *(half8v*)&WL[gi * 2 + q][tid][0] = hi;
    }
#pragma unroll
    for (int r = 0; r < 4; ++r) {
      const int n = 64 * gi + 16 * w + 4 * tg + r;
      dbsv[gi][r] = (dbih[n] + dbhh[n]) * gsc;
    }
  }
#pragma unroll
  for (int q = 0; q < 2; ++q) {
    half8v hi = hz8;
    if (m < 2) {
      const int k0 = 32 * q + 8 * tg;
#pragma unroll
      for (int e = 0; e < 4; ++e) {
        hi[e]     = (_Float16)linW[m * 64 + k0 + e];
        hi[4 + e] = (_Float16)linW[m * 64 + k0 + e + 4];
      }
    }
    *(half8v*)&WL[8 + q][tid][0] = hi;
  }
  float4v lbinit = {0.f, 0.f, 0.f, 0.f};
  if (tg == 0) { lbinit[0] = linb[0]; lbinit[1] = linb[1]; }
  __syncthreads();   // decoder WL ready

  // ---- decoder: 30 steps; out[st] emitted via MFMA after the exchange ----
#pragma unroll 1
  for (int st = 0; st < 30; ++st) {
    short4v hh0, hh1;
    {
      float4v a0[4];
#pragma unroll
      for (int gi = 0; gi < 4; ++gi) {
        half8v f0 = *(const half8v*)&WL[gi * 2 + 0][tid][0];
        half8v f1 = *(const half8v*)&WL[gi * 2 + 1][tid][0];
        float4v a = MFMAH(f0, b0[0], dbsv[gi]);
        a0[gi] = MFMAH(f1, b0[1], a);
      }
      cellact(a0, c0, hh0);
    }
    {
      float4v a1[4];
#pragma unroll
      for (int gi = 0; gi < 4; ++gi) {
        half8v f0 = *(const half8v*)&WL[gi * 2 + 0][tid][0];
        half8v f1 = *(const half8v*)&WL[gi * 2 + 1][tid][0];
        float4v a = MFMAH(f0, b1[0], dbsv[gi]);
        a1[gi] = MFMAH(f1, b1[1], a);
      }
      cellact(a1, c1, hh1);
    }
    *(short4v*)&Hh[p][m][wslot]      = hh0;
    *(short4v*)&Hh[p][m + 16][wslot] = hh1;
    __syncthreads();
#pragma unroll
    for (int q = 0; q < 2; ++q) {
      const int rs = (((8 * q) | (2 * tg)) ^ msk) << 2;
      b0[q] = *(const half8v*)&Hh[p][m][rs];
      b1[q] = *(const half8v*)&Hh[p][m + 16][rs];
    }
    // b-frags now hold h_st -> emit out[st] on the matrix pipe.
    if (w == 0) {
      half8v L0 = *(const half8v*)&WL[8][tid][0];
      half8v L1 = *(const half8v*)&WL[9][tid][0];
      float4v la = lbinit;
      la = MFMAH(L0, b0[0], la);
      la = MFMAH(L1, b0[1], la);
      if (l < 16 && (bg + l) < B) {
        size_t oidx = ((size_t)(bg + l) * 30 + st) * 2;
        *(float2*)&out[oidx] = make_float2(la[0], la[1]);
      }
    } else if (w == 1) {
      half8v L0 = *(const half8v*)&WL[8][tid][0];
      half8v L1 = *(const half8v*)&WL[9][tid][0];
      float4v la = lbinit;
      la = MFMAH(L0, b1[0], la);
      la = MFMAH(L1, b1[1], la);
      if (l < 16 && (bg + 16 + l) < B) {
        size_t oidx = ((size_t)(bg + 16 + l) * 30 + st) * 2;
        *(float2*)&out[oidx] = make_float2(la[0], la[1]);
      }
    }
    p ^= 1;
  }
}

extern "C" void kernel_launch(void* const* d_in, const int* in_sizes, int n_in,
                              void* d_out, int out_size, void* d_ws, size_t ws_size,
                              hipStream_t stream) {
  (void)n_in; (void)out_size; (void)d_ws; (void)ws_size;
  const float* x    = (const float*)d_in[0];
  const float* eWih = (const float*)d_in[1];
  const float* eWhh = (const float*)d_in[2];
  const float* ebih = (const float*)d_in[3];
  const float* ebhh = (const float*)d_in[4];
  const float* dWih = (const float*)d_in[5];
  const float* dWhh = (const float*)d_in[6];
  const float* dbih = (const float*)d_in[7];
  const float* dbhh = (const float*)d_in[8];
  const float* linW = (const float*)d_in[9];
  const float* linb = (const float*)d_in[10];

  const int B = in_sizes[0] / 40;          // [B][20][2]
  const int grid = (B + 31) / 32;          // 32 batch elems per block (2 tiles)
  lstm_fused<<<grid, 256, 0, stream>>>(x, eWih, eWhh, ebih, ebhh,
                                       dWih, dWhh, dbih, dbhh, linW, linb,
                                       (float*)d_out, B);
}

// Round 12
// 441.940 us; speedup vs baseline: 1.5393x; 1.5393x over previous
//
#include <hip/hip_runtime.h>

// LSTM enc(20, in=2) + dec(30, in=h) fused, HID=64, f32 I/O.
// Gates-transposed MFMA recurrence, v_mfma_f32_16x16x32_f16 (K=32).
//   D[n][m] = sum_k W[n][k] h[m][k]; C/D: col=l&15, row=4*(l>>4)+r.
// k-relabeling f(q,tg,e) = 32q+8tg+e on BOTH operands (bijection -> D
// unchanged): A-frag q = 8 contiguous W[n][32q+8tg..+7], B-frag q =
// h[32q+8tg..+7] from identity-layout LDS.  Wave w owns hidden
// [16w,16w+16); h exchanged via dbuf XOR-swizzled Hh, 1 barrier/step.
// x-projection = 3rd MFMA (q2): A=[Wa,Wb,bias]*gsc (tg0), B=[xa,xb,1]f16.
// TWO batch tiles/block (32 batch), (256,3), W frags in LDS (R13).
//
// R8/R9: f16 scheme: 16 gate-MFMAs/step; absmax floor 2.4e-4.
// R10-R12: allocator clamp = 2x-unified split: (256,2)->108, (256,3)->84,
//   (256,4)->64 arch VGPRs; spills catastrophic.
// R13: W frags + x-proj evicted to LDS/MFMA: no spill, VGPR 68, wall 432,
//   rocprof 490.  Best passing baseline.
// R14 FAILED: (256,4) 1-tile: occ 45% but VALUBusy stuck ~71.  MODEL:
//   VALUBusy+MfmaUtil = 93-97% everywhere -> ONE shared SIMD issue
//   budget; only lever is fewer issue cycles.
// R15 FAILED correctness: magic-add round folded by value-unsafe FP ->
//   exp2 became a step function.  (rcp_pair exonerated by R16.)
// R16 FAILED perf: fold-proof poly exp2 (rintf/ldexpf/deg-5) PASSED
//   absmax 2.4e-4 but VALU issue ~2.4x: ldexpf/cvt expand to long
//   full-rate sequences; 20/cellact swamp the 16-cy trans they replace.
//   LESSON: hw quarter-rate trans is cheaper than any >=4-inst/value
//   full-rate polynomial.  rocprof ~800.
// R17 (this round): stated fallback = R13 + hw exp2 + rcp_pair ONLY
//   (combination numerically proven by R16's pass).  Per cellact:
//   20 exp2 + 4 rcp (was +8): trans/wave-step 896 -> 768 cy, +~16cy
//   pairing muls.  Inventory 768+146+396 ~= 1310/1470.  Predict
//   rocprof 490 -> 455-470, wall 432 -> 405-420, VALU ~67, Mfma ~27,
//   absmax 2.4e-4.  If slower than 490: rcp-mul serialization costs
//   more than its issue saving -> pure R13 is the structural floor.

#define LOG2E 1.44269504088896340736f
#define TWO_LOG2E 2.88539008177792681472f

typedef __attribute__((ext_vector_type(4))) short short4v;
typedef __attribute__((ext_vector_type(4))) float float4v;
typedef __attribute__((ext_vector_type(4))) unsigned int uint4v;
typedef _Float16 __attribute__((ext_vector_type(8))) half8v;

#if defined(__HIP_DEVICE_COMPILE__)
#define MFMAH(a, b, c) __builtin_amdgcn_mfma_f32_16x16x32_f16((a), (b), (c), 0, 0, 0)
#else
#define MFMAH(a, b, c) (c)
#endif

__device__ __forceinline__ float4v exp2v4(float4v x) {
  float4v r;
  r[0] = __builtin_amdgcn_exp2f(x[0]);
  r[1] = __builtin_amdgcn_exp2f(x[1]);
  r[2] = __builtin_amdgcn_exp2f(x[2]);
  r[3] = __builtin_amdgcn_exp2f(x[3]);
  return r;
}

// 1/d elementwise with rcps PAIRED across (0,1) and (2,3):
// r01 = rcp(d0*d1); 1/d0 = d1*r01, 1/d1 = d0*r01.  2 trans instead of 4.
// Overflow-safe: pair product <= ~1e29 << f32 max for bounded gates.
// Numerically proven in R16 (absmax 2.4e-4).
__device__ __forceinline__ float4v rcp_pair(float4v d) {
  float r01 = __builtin_amdgcn_rcpf(d[0] * d[1]);
  float r23 = __builtin_amdgcn_rcpf(d[2] * d[3]);
  float4v r;
  r[0] = d[1] * r01;
  r[1] = d[0] * r01;
  r[2] = d[3] * r23;
  r[3] = d[2] * r23;
  return r;
}

// Fused LSTM cell update on 4 rows (pk-f32).  a[0..3] = gates i,f,g,o
// PRE-SCALED (i,f,o by -log2e; g by 2log2e).  c holds 2log2e*cell.
__device__ __forceinline__ void cellact(const float4v* a, float4v& c,
                                        short4v& hh) {
  const float4v one = {1.f, 1.f, 1.f, 1.f};
  const float4v clo = {-36.f, -36.f, -36.f, -36.f};
  const float4v chi = {36.f, 36.f, 36.f, 36.f};
  float4v Ei = exp2v4(a[0]);                    // e^{-i}
  float4v Ef = exp2v4(a[1]);                    // e^{-f}
  float4v Eg = exp2v4(a[2]);                    // e^{2g}
  float4v Eo = exp2v4(a[3]);                    // e^{-o}
  float4v t3 = one + Ef;
  float4v P  = (one + Ei) * (one + Eg);
  float4v t4s = Eg * TWO_LOG2E - TWO_LOG2E;     // 2log2e*(Eg-1)
  float4v num = c * P + t4s * t3;
  float4v cs = num * rcp_pair(P * t3);          // 2log2e * c_new
  c = cs;
  float4v cl = __builtin_elementwise_min(__builtin_elementwise_max(cs, clo), chi);
  float4v Ec = exp2v4(cl);
  float4v h = (Ec - one) * rcp_pair((one + Ec) * (one + Eo));
#pragma unroll
  for (int r = 0; r < 4; ++r) {
    _Float16 hf = (_Float16)h[r];               // v_cvt_f16_f32 (RNE)
    hh[r] = (short)__builtin_bit_cast(unsigned short, hf);
  }
}

__global__ __launch_bounds__(256, 3) void lstm_fused(
    const float* __restrict__ x,     // [B][20][2]
    const float* __restrict__ eWih,  // [256][2]
    const float* __restrict__ eWhh,  // [256][64]
    const float* __restrict__ ebih,  // [256]
    const float* __restrict__ ebhh,  // [256]
    const float* __restrict__ dWih,  // [256][64]
    const float* __restrict__ dWhh,  // [256][64]
    const float* __restrict__ dbih,  // [256]
    const float* __restrict__ dbhh,  // [256]
    const float* __restrict__ linW,  // [2][64]
    const float* __restrict__ linb,  // [2]
    float* __restrict__ out,         // [B][30][2]
    int B) {
  const int tid = threadIdx.x;
  const int w   = tid >> 6;    // wave: hidden block [16w, 16w+16)
  const int l   = tid & 63;
  const int m   = l & 15;      // batch col within tile
  const int tg  = l >> 4;
  const int msk = m & 14;
  const int wslot = (((w << 2) | tg) ^ msk) << 2;   // halfword off, b64 write
  const int bg  = blockIdx.x * 32;

  __shared__ __align__(16) unsigned short WL[10][256][8];  // W/LA frags, f16
  __shared__ __align__(16) unsigned short Hh[2][32][64];   // h, f16 bits
  __shared__ unsigned int Xs16[32][21];                    // packed f16 x

  const half8v hz8 = {0, 0, 0, 0, 0, 0, 0, 0};
  const float4v zf = {0.f, 0.f, 0.f, 0.f};

  // ---- stage x as packed f16 pairs: Xs16[mm][st] = (xb|xa) ----
  {
    const size_t xoff = (size_t)blockIdx.x * 1280;
    for (int i = tid; i < 640; i += 256) {
      int mm = i / 20, st = i - mm * 20;
      size_t g = xoff + (size_t)mm * 40 + st * 2;
      float xa = 0.f, xb = 0.f;
      if (g + 1 < (size_t)B * 40) { xa = x[g]; xb = x[g + 1]; }
      unsigned ua = __builtin_bit_cast(unsigned short, (_Float16)xa);
      unsigned ub = __builtin_bit_cast(unsigned short, (_Float16)xb);
      Xs16[mm][st] = (ub << 16) | ua;
    }
  }

  // ---- encoder weights: Whh frags -> WL[0..7]; x/bias frag q2 in regs ----
  half8v eA2[4];
#pragma unroll
  for (int gi = 0; gi < 4; ++gi) {
    const float gsc = (gi == 2) ? TWO_LOG2E : -LOG2E;
    const int nA = m + 16 * (4 * gi + w);
#pragma unroll
    for (int q = 0; q < 2; ++q) {
      const float* wp = &eWhh[nA * 64 + 32 * q + 8 * tg];
      float4v w0 = *(const float4v*)wp;
      float4v w1 = *(const float4v*)(wp + 4);
      half8v hi;
#pragma unroll
      for (int e = 0; e < 4; ++e) {
        hi[e]     = (_Float16)(w0[e] * gsc);
        hi[4 + e] = (_Float16)(w1[e] * gsc);
      }
      *(half8v*)&WL[gi * 2 + q][tid][0] = hi;
    }
    half8v a2 = hz8;
    if (tg == 0) {
      a2[0] = (_Float16)(eWih[nA * 2 + 0] * gsc);
      a2[1] = (_Float16)(eWih[nA * 2 + 1] * gsc);
      a2[2] = (_Float16)((ebih[nA] + ebhh[nA]) * gsc);
    }
    eA2[gi] = a2;
  }

  __syncthreads();   // Xs16 + WL ready

  float4v c0 = {0.f, 0.f, 0.f, 0.f}, c1 = {0.f, 0.f, 0.f, 0.f};
  half8v b0[2] = {hz8, hz8}, b1[2] = {hz8, hz8};
  int p = 0;

  // ---- encoder: 20 steps (tile-sequential; frags re-read per tile) ----
#pragma unroll 1
  for (int st = 0; st < 20; ++st) {
    short4v hh0, hh1;
    {
      uint4v t; t[0] = Xs16[m][st]; t[1] = 0x3C00u; t[2] = 0u; t[3] = 0u;
      half8v bq2 = (tg == 0) ? __builtin_bit_cast(half8v, t) : hz8;
      float4v a0[4];
#pragma unroll
      for (int gi = 0; gi < 4; ++gi) {
        half8v f0 = *(const half8v*)&WL[gi * 2 + 0][tid][0];
        half8v f1 = *(const half8v*)&WL[gi * 2 + 1][tid][0];
        float4v a = MFMAH(eA2[gi], bq2, zf);
        a = MFMAH(f0, b0[0], a);
        a0[gi] = MFMAH(f1, b0[1], a);
      }
      cellact(a0, c0, hh0);
    }
    {
      uint4v t; t[0] = Xs16[m + 16][st]; t[1] = 0x3C00u; t[2] = 0u; t[3] = 0u;
      half8v bq2 = (tg == 0) ? __builtin_bit_cast(half8v, t) : hz8;
      float4v a1[4];
#pragma unroll
      for (int gi = 0; gi < 4; ++gi) {
        half8v f0 = *(const half8v*)&WL[gi * 2 + 0][tid][0];
        half8v f1 = *(const half8v*)&WL[gi * 2 + 1][tid][0];
        float4v a = MFMAH(eA2[gi], bq2, zf);
        a = MFMAH(f0, b1[0], a);
        a1[gi] = MFMAH(f1, b1[1], a);
      }
      cellact(a1, c1, hh1);
    }
    *(short4v*)&Hh[p][m][wslot]      = hh0;
    *(short4v*)&Hh[p][m + 16][wslot] = hh1;
    __syncthreads();
#pragma unroll
    for (int q = 0; q < 2; ++q) {
      const int rs = (((8 * q) | (2 * tg)) ^ msk) << 2;
      b0[q] = *(const half8v*)&Hh[p][m][rs];
      b1[q] = *(const half8v*)&Hh[p][m + 16][rs];
    }
    p ^= 1;
  }

  // ---- transition: repack WL with decoder Wsum + LA; dbsv in regs ----
  // (legal: every encoder WL read precedes the step-19 barrier)
  float4v dbsv[4];
#pragma unroll
  for (int gi = 0; gi < 4; ++gi) {
    const float gsc = (gi == 2) ? TWO_LOG2E : -LOG2E;
    const int nA = m + 16 * (4 * gi + w);
#pragma unroll
    for (int q = 0; q < 2; ++q) {
      const float* wpa = &dWih[nA * 64 + 32 * q + 8 * tg];
      const float* wpb = &dWhh[nA * 64 + 32 * q + 8 * tg];
      float4v a0v = *(const float4v*)wpa;
      float4v a1v = *(const float4v*)(wpa + 4);
      float4v b0v = *(const float4v*)wpb;
      float4v b1v = *(const float4v*)(wpb + 4);
      half8v hi;
#pragma unroll
      for (int e = 0; e < 4; ++e) {
        hi[e]     = (_Float16)((a0v[e] + b0v[e]) * gsc);
        hi[4 + e] = (_Float16)((a1v[e] + b1v[e]) * gsc);
      }
      *(half8v*)&WL[gi * 2 + q][tid][0] = hi;
    }
#pragma unroll
    for (int r = 0; r < 4; ++r) {
      const int n = 64 * gi + 16 * w + 4 * tg + r;
      dbsv[gi][r] = (dbih[n] + dbhh[n]) * gsc;
    }
  }
#pragma unroll
  for (int q = 0; q < 2; ++q) {
    half8v hi = hz8;
    if (m < 2) {
      const int k0 = 32 * q + 8 * tg;
#pragma unroll
      for (int e = 0; e < 4; ++e) {
        hi[e]     = (_Float16)linW[m * 64 + k0 + e];
        hi[4 + e] = (_Float16)linW[m * 64 + k0 + e + 4];
      }
    }
    *(half8v*)&WL[8 + q][tid][0] = hi;
  }
  float4v lbinit = {0.f, 0.f, 0.f, 0.f};
  if (tg == 0) { lbinit[0] = linb[0]; lbinit[1] = linb[1]; }
  __syncthreads();   // decoder WL ready

  // ---- decoder: 30 steps; out[st] emitted via MFMA after the exchange ----
#pragma unroll 1
  for (int st = 0; st < 30; ++st) {
    short4v hh0, hh1;
    {
      float4v a0[4];
#pragma unroll
      for (int gi = 0; gi < 4; ++gi) {
        half8v f0 = *(const half8v*)&WL[gi * 2 + 0][tid][0];
        half8v f1 = *(const half8v*)&WL[gi * 2 + 1][tid][0];
        float4v a = MFMAH(f0, b0[0], dbsv[gi]);
        a0[gi] = MFMAH(f1, b0[1], a);
      }
      cellact(a0, c0, hh0);
    }
    {
      float4v a1[4];
#pragma unroll
      for (int gi = 0; gi < 4; ++gi) {
        half8v f0 = *(const half8v*)&WL[gi * 2 + 0][tid][0];
        half8v f1 = *(const half8v*)&WL[gi * 2 + 1][tid][0];
        float4v a = MFMAH(f0, b1[0], dbsv[gi]);
        a1[gi] = MFMAH(f1, b1[1], a);
      }
      cellact(a1, c1, hh1);
    }
    *(short4v*)&Hh[p][m][wslot]      = hh0;
    *(short4v*)&Hh[p][m + 16][wslot] = hh1;
    __syncthreads();
#pragma unroll
    for (int q = 0; q < 2; ++q) {
      const int rs = (((8 * q) | (2 * tg)) ^ msk) << 2;
      b0[q] = *(const half8v*)&Hh[p][m][rs];
      b1[q] = *(const half8v*)&Hh[p][m + 16][rs];
    }
    // b-frags now hold h_st -> emit out[st] on the matrix pipe.
    if (w == 0) {
      half8v L0 = *(const half8v*)&WL[8][tid][0];
      half8v L1 = *(const half8v*)&WL[9][tid][0];
      float4v la = lbinit;
      la = MFMAH(L0, b0[0], la);
      la = MFMAH(L1, b0[1], la);
      if (l < 16 && (bg + l) < B) {
        size_t oidx = ((size_t)(bg + l) * 30 + st) * 2;
        *(float2*)&out[oidx] = make_float2(la[0], la[1]);
      }
    } else if (w == 1) {
      half8v L0 = *(const half8v*)&WL[8][tid][0];
      half8v L1 = *(const half8v*)&WL[9][tid][0];
      float4v la = lbinit;
      la = MFMAH(L0, b1[0], la);
      la = MFMAH(L1, b1[1], la);
      if (l < 16 && (bg + 16 + l) < B) {
        size_t oidx = ((size_t)(bg + 16 + l) * 30 + st) * 2;
        *(float2*)&out[oidx] = make_float2(la[0], la[1]);
      }
    }
    p ^= 1;
  }
}

extern "C" void kernel_launch(void* const* d_in, const int* in_sizes, int n_in,
                              void* d_out, int out_size, void* d_ws, size_t ws_size,
                              hipStream_t stream) {
  (void)n_in; (void)out_size; (void)d_ws; (void)ws_size;
  const float* x    = (const float*)d_in[0];
  const float* eWih = (const float*)d_in[1];
  const float* eWhh = (const float*)d_in[2];
  const float* ebih = (const float*)d_in[3];
  const float* ebhh = (const float*)d_in[4];
  const float* dWih = (const float*)d_in[5];
  const float* dWhh = (const float*)d_in[6];
  const float* dbih = (const float*)d_in[7];
  const float* dbhh = (const float*)d_in[8];
  const float* linW = (const float*)d_in[9];
  const float* linb = (const float*)d_in[10];

  const int B = in_sizes[0] / 40;          // [B][20][2]
  const int grid = (B + 31) / 32;          // 32 batch elems per block (2 tiles)
  lstm_fused<<<grid, 256, 0, stream>>>(x, eWih, eWhh, ebih, ebhh,
                                       dWih, dWhh, dbih, dbhh, linW, linb,
                                       (float*)d_out, B);
}

// Round 13
// 433.048 us; speedup vs baseline: 1.5709x; 1.0205x over previous
//
#include <hip/hip_runtime.h>

// LSTM enc(20, in=2) + dec(30, in=h) fused, HID=64, f32 I/O.
// Gates-transposed MFMA recurrence, v_mfma_f32_16x16x32_f16 (K=32).
//   D[n][m] = sum_k W[n][k] h[m][k]; C/D: col=l&15, row=4*(l>>4)+r.
// k-relabeling f(q,tg,e) = 32q+8tg+e on BOTH operands (bijection -> D
// unchanged): A-frag q = 8 contiguous W[n][32q+8tg..+7], B-frag q =
// h[32q+8tg..+7] from identity-layout LDS.  Wave w owns hidden
// [16w,16w+16); h exchanged via dbuf XOR-swizzled Hh, 1 barrier/step.
// x-projection = 3rd MFMA (q2): A=[Wa,Wb,bias]*gsc (tg0), B=[xa,xb,1]f16.
// TWO batch tiles/block (32 batch), (256,3), W frags in LDS.
//
// FINAL (R18) = exact R13, the measured optimum (wall 432us, rocprof
// 490, absmax 2.4e-4).  Session ladder (rocprof us): 886 -> 830 (R6
// exp2-domain gates + single-rcp cell) -> 850 (R7 pk-f32) -> 655 (R8
// f16-RNE h, no h-lo) -> 548 (R9 single-f16 W) -> 490 (R13 W-frags +
// x-proj evicted to LDS/MFMA, no spill).  Wall 755 -> 432.
//
// Why this is the structural roofline:
//  - VALUBusy + MfmaUtil = 93-97% in every healthy config (R11-R17):
//    ONE shared SIMD issue budget, saturated.
//  - Trans floor: 5 exp2 + 2 rcp per h is the algebraic minimum for the
//    exponential-form cell (R6).  Poly exp2 = 2.4x issue (R16 — ldexpf/
//    cvt expand to long full-rate sequences; quarter-rate hw trans beats
//    any >=4-inst/value replacement).  rcp pairing = latency-negative
//    (R17 — dependent mul->rcp->mul chain outweighs -128 issue cy).
//  - Occupancy: 4 streams/SIMD at occ 45% was SLOWER (R14) — no idle
//    claimable by TLP at this saturation.  Register clamps = 2x-unified
//    split: (256,2)->108, (256,3)->84, (256,4)->64 (R10-R12); spills
//    catastrophic; demand 68 fits (256,3) clean.
//  - MFMA floor: 16+2 MFMAs/step minimal for 3-operand f16 form; absmax
//    pinned at the 2.4e-4 harness floor since R8.
//  Remaining gap to the ~350us VALU-issue floor is dependency stall
//  that neither TLP (R14) nor fewer instructions (R15-R17) can buy.

#define LOG2E 1.44269504088896340736f
#define TWO_LOG2E 2.88539008177792681472f

typedef __attribute__((ext_vector_type(4))) short short4v;
typedef __attribute__((ext_vector_type(4))) float float4v;
typedef __attribute__((ext_vector_type(4))) unsigned int uint4v;
typedef _Float16 __attribute__((ext_vector_type(8))) half8v;

#if defined(__HIP_DEVICE_COMPILE__)
#define MFMAH(a, b, c) __builtin_amdgcn_mfma_f32_16x16x32_f16((a), (b), (c), 0, 0, 0)
#else
#define MFMAH(a, b, c) (c)
#endif

__device__ __forceinline__ float4v exp2v4(float4v x) {
  float4v r;
  r[0] = __builtin_amdgcn_exp2f(x[0]);
  r[1] = __builtin_amdgcn_exp2f(x[1]);
  r[2] = __builtin_amdgcn_exp2f(x[2]);
  r[3] = __builtin_amdgcn_exp2f(x[3]);
  return r;
}
__device__ __forceinline__ float4v rcpv4(float4v x) {
  float4v r;
  r[0] = __builtin_amdgcn_rcpf(x[0]);
  r[1] = __builtin_amdgcn_rcpf(x[1]);
  r[2] = __builtin_amdgcn_rcpf(x[2]);
  r[3] = __builtin_amdgcn_rcpf(x[3]);
  return r;
}

// Fused LSTM cell update on 4 rows (pk-f32).  a[0..3] = gates i,f,g,o
// PRE-SCALED (i,f,o by -log2e; g by 2log2e).  c holds 2log2e*cell.
__device__ __forceinline__ void cellact(const float4v* a, float4v& c,
                                        short4v& hh) {
  const float4v one = {1.f, 1.f, 1.f, 1.f};
  const float4v clo = {-36.f, -36.f, -36.f, -36.f};
  const float4v chi = {36.f, 36.f, 36.f, 36.f};
  float4v Ei = exp2v4(a[0]);                    // e^{-i}
  float4v Ef = exp2v4(a[1]);                    // e^{-f}
  float4v Eg = exp2v4(a[2]);                    // e^{2g}
  float4v Eo = exp2v4(a[3]);                    // e^{-o}
  float4v t1 = one + Ei;
  float4v t2 = one + Eg;
  float4v t3 = one + Ef;
  float4v t4s = Eg * TWO_LOG2E - TWO_LOG2E;     // 2log2e*(Eg-1)
  float4v P = t1 * t2;
  float4v num = c * P + t4s * t3;
  float4v cs = num * rcpv4(P * t3);             // 2log2e * c_new
  c = cs;
  float4v cl = __builtin_elementwise_min(__builtin_elementwise_max(cs, clo), chi);
  float4v Ec = exp2v4(cl);
  float4v h = (Ec - one) * rcpv4((one + Ec) * (one + Eo));
#pragma unroll
  for (int r = 0; r < 4; ++r) {
    _Float16 hf = (_Float16)h[r];               // v_cvt_f16_f32 (RNE)
    hh[r] = (short)__builtin_bit_cast(unsigned short, hf);
  }
}

__global__ __launch_bounds__(256, 3) void lstm_fused(
    const float* __restrict__ x,     // [B][20][2]
    const float* __restrict__ eWih,  // [256][2]
    const float* __restrict__ eWhh,  // [256][64]
    const float* __restrict__ ebih,  // [256]
    const float* __restrict__ ebhh,  // [256]
    const float* __restrict__ dWih,  // [256][64]
    const float* __restrict__ dWhh,  // [256][64]
    const float* __restrict__ dbih,  // [256]
    const float* __restrict__ dbhh,  // [256]
    const float* __restrict__ linW,  // [2][64]
    const float* __restrict__ linb,  // [2]
    float* __restrict__ out,         // [B][30][2]
    int B) {
  const int tid = threadIdx.x;
  const int w   = tid >> 6;    // wave: hidden block [16w, 16w+16)
  const int l   = tid & 63;
  const int m   = l & 15;      // batch col within tile
  const int tg  = l >> 4;
  const int msk = m & 14;
  const int wslot = (((w << 2) | tg) ^ msk) << 2;   // halfword off, b64 write
  const int bg  = blockIdx.x * 32;

  __shared__ __align__(16) unsigned short WL[10][256][8];  // W/LA frags, f16
  __shared__ __align__(16) unsigned short Hh[2][32][64];   // h, f16 bits
  __shared__ unsigned int Xs16[32][21];                    // packed f16 x

  const half8v hz8 = {0, 0, 0, 0, 0, 0, 0, 0};
  const float4v zf = {0.f, 0.f, 0.f, 0.f};

  // ---- stage x as packed f16 pairs: Xs16[mm][st] = (xb|xa) ----
  {
    const size_t xoff = (size_t)blockIdx.x * 1280;
    for (int i = tid; i < 640; i += 256) {
      int mm = i / 20, st = i - mm * 20;
      size_t g = xoff + (size_t)mm * 40 + st * 2;
      float xa = 0.f, xb = 0.f;
      if (g + 1 < (size_t)B * 40) { xa = x[g]; xb = x[g + 1]; }
      unsigned ua = __builtin_bit_cast(unsigned short, (_Float16)xa);
      unsigned ub = __builtin_bit_cast(unsigned short, (_Float16)xb);
      Xs16[mm][st] = (ub << 16) | ua;
    }
  }

  // ---- encoder weights: Whh frags -> WL[0..7]; x/bias frag q2 in regs ----
  half8v eA2[4];
#pragma unroll
  for (int gi = 0; gi < 4; ++gi) {
    const float gsc = (gi == 2) ? TWO_LOG2E : -LOG2E;
    const int nA = m + 16 * (4 * gi + w);
#pragma unroll
    for (int q = 0; q < 2; ++q) {
      const float* wp = &eWhh[nA * 64 + 32 * q + 8 * tg];
      float4v w0 = *(const float4v*)wp;
      float4v w1 = *(const float4v*)(wp + 4);
      half8v hi;
#pragma unroll
      for (int e = 0; e < 4; ++e) {
        hi[e]     = (_Float16)(w0[e] * gsc);
        hi[4 + e] = (_Float16)(w1[e] * gsc);
      }
      *(half8v*)&WL[gi * 2 + q][tid][0] = hi;
    }
    half8v a2 = hz8;
    if (tg == 0) {
      a2[0] = (_Float16)(eWih[nA * 2 + 0] * gsc);
      a2[1] = (_Float16)(eWih[nA * 2 + 1] * gsc);
      a2[2] = (_Float16)((ebih[nA] + ebhh[nA]) * gsc);
    }
    eA2[gi] = a2;
  }

  __syncthreads();   // Xs16 + WL ready

  float4v c0 = {0.f, 0.f, 0.f, 0.f}, c1 = {0.f, 0.f, 0.f, 0.f};
  half8v b0[2] = {hz8, hz8}, b1[2] = {hz8, hz8};
  int p = 0;

  // ---- encoder: 20 steps (tile-sequential; frags re-read per tile) ----
#pragma unroll 1
  for (int st = 0; st < 20; ++st) {
    short4v hh0, hh1;
    {
      uint4v t; t[0] = Xs16[m][st]; t[1] = 0x3C00u; t[2] = 0u; t[3] = 0u;
      half8v bq2 = (tg == 0) ? __builtin_bit_cast(half8v, t) : hz8;
      float4v a0[4];
#pragma unroll
      for (int gi = 0; gi < 4; ++gi) {
        half8v f0 = *(const half8v*)&WL[gi * 2 + 0][tid][0];
        half8v f1 = *(const half8v*)&WL[gi * 2 + 1][tid][0];
        float4v a = MFMAH(eA2[gi], bq2, zf);
        a = MFMAH(f0, b0[0], a);
        a0[gi] = MFMAH(f1, b0[1], a);
      }
      cellact(a0, c0, hh0);
    }
    {
      uint4v t; t[0] = Xs16[m + 16][st]; t[1] = 0x3C00u; t[2] = 0u; t[3] = 0u;
      half8v bq2 = (tg == 0) ? __builtin_bit_cast(half8v, t) : hz8;
      float4v a1[4];
#pragma unroll
      for (int gi = 0; gi < 4; ++gi) {
        half8v f0 = *(const half8v*)&WL[gi * 2 + 0][tid][0];
        half8v f1 = *(const half8v*)&WL[gi * 2 + 1][tid][0];
        float4v a = MFMAH(eA2[gi], bq2, zf);
        a = MFMAH(f0, b1[0], a);
        a1[gi] = MFMAH(f1, b1[1], a);
      }
      cellact(a1, c1, hh1);
    }
    *(short4v*)&Hh[p][m][wslot]      = hh0;
    *(short4v*)&Hh[p][m + 16][wslot] = hh1;
    __syncthreads();
#pragma unroll
    for (int q = 0; q < 2; ++q) {
      const int rs = (((8 * q) | (2 * tg)) ^ msk) << 2;
      b0[q] = *(const half8v*)&Hh[p][m][rs];
      b1[q] = *(const half8v*)&Hh[p][m + 16][rs];
    }
    p ^= 1;
  }

  // ---- transition: repack WL with decoder Wsum + LA; dbsv in regs ----
  // (legal: every encoder WL read precedes the step-19 barrier)
  float4v dbsv[4];
#pragma unroll
  for (int gi = 0; gi < 4; ++gi) {
    const float gsc = (gi == 2) ? TWO_LOG2E : -LOG2E;
    const int nA = m + 16 * (4 * gi + w);
#pragma unroll
    for (int q = 0; q < 2; ++q) {
      const float* wpa = &dWih[nA * 64 + 32 * q + 8 * tg];
      const float* wpb = &dWhh[nA * 64 + 32 * q + 8 * tg];
      float4v a0v = *(const float4v*)wpa;
      float4v a1v = *(const float4v*)(wpa + 4);
      float4v b0v = *(const float4v*)wpb;
      float4v b1v = *(const float4v*)(wpb + 4);
      half8v hi;
#pragma unroll
      for (int e = 0; e < 4; ++e) {
        hi[e]     = (_Float16)((a0v[e] + b0v[e]) * gsc);
        hi[4 + e] = (_Float16)((a1v[e] + b1v[e]) * gsc);
      }
      *(half8v*)&WL[gi * 2 + q][tid][0] = hi;
    }
#pragma unroll
    for (int r = 0; r < 4; ++r) {
      const int n = 64 * gi + 16 * w + 4 * tg + r;
      dbsv[gi][r] = (dbih[n] + dbhh[n]) * gsc;
    }
  }
#pragma unroll
  for (int q = 0; q < 2; ++q) {
    half8v hi = hz8;
    if (m < 2) {
      const int k0 = 32 * q + 8 * tg;
#pragma unroll
      for (int e = 0; e < 4; ++e) {
        hi[e]     = (_Float16)linW[m * 64 + k0 + e];
        hi[4 + e] = (_Float16)linW[m * 64 + k0 + e + 4];
      }
    }
    *(half8v*)&WL[8 + q][tid][0] = hi;
  }
  float4v lbinit = {0.f, 0.f, 0.f, 0.f};
  if (tg == 0) { lbinit[0] = linb[0]; lbinit[1] = linb[1]; }
  __syncthreads();   // decoder WL ready

  // ---- decoder: 30 steps; out[st] emitted via MFMA after the exchange ----
#pragma unroll 1
  for (int st = 0; st < 30; ++st) {
    short4v hh0, hh1;
    {
      float4v a0[4];
#pragma unroll
      for (int gi = 0; gi < 4; ++gi) {
        half8v f0 = *(const half8v*)&WL[gi * 2 + 0][tid][0];
        half8v f1 = *(const half8v*)&WL[gi * 2 + 1][tid][0];
        float4v a = MFMAH(f0, b0[0], dbsv[gi]);
        a0[gi] = MFMAH(f1, b0[1], a);
      }
      cellact(a0, c0, hh0);
    }
    {
      float4v a1[4];
#pragma unroll
      for (int gi = 0; gi < 4; ++gi) {
        half8v f0 = *(const half8v*)&WL[gi * 2 + 0][tid][0];
        half8v f1 = *(const half8v*)&WL[gi * 2 + 1][tid][0];
        float4v a = MFMAH(f0, b1[0], dbsv[gi]);
        a1[gi] = MFMAH(f1, b1[1], a);
      }
      cellact(a1, c1, hh1);
    }
    *(short4v*)&Hh[p][m][wslot]      = hh0;
    *(short4v*)&Hh[p][m + 16][wslot] = hh1;
    __syncthreads();
#pragma unroll
    for (int q = 0; q < 2; ++q) {
      const int rs = (((8 * q) | (2 * tg)) ^ msk) << 2;
      b0[q] = *(const half8v*)&Hh[p][m][rs];
      b1[q] = *(const half8v*)&Hh[p][m + 16][rs];
    }
    // b-frags now hold h_st -> emit out[st] on the matrix pipe.
    if (w == 0) {
      half8v L0 = *(const half8v*)&WL[8][tid][0];
      half8v L1 = *(const half8v*)&WL[9][tid][0];
      float4v la = lbinit;
      la = MFMAH(L0, b0[0], la);
      la = MFMAH(L1, b0[1], la);
      if (l < 16 && (bg + l) < B) {
        size_t oidx = ((size_t)(bg + l) * 30 + st) * 2;
        *(float2*)&out[oidx] = make_float2(la[0], la[1]);
      }
    } else if (w == 1) {
      half8v L0 = *(const half8v*)&WL[8][tid][0];
      half8v L1 = *(const half8v*)&WL[9][tid][0];
      float4v la = lbinit;
      la = MFMAH(L0, b1[0], la);
      la = MFMAH(L1, b1[1], la);
      if (l < 16 && (bg + 16 + l) < B) {
        size_t oidx = ((size_t)(bg + 16 + l) * 30 + st) * 2;
        *(float2*)&out[oidx] = make_float2(la[0], la[1]);
      }
    }
    p ^= 1;
  }
}

extern "C" void kernel_launch(void* const* d_in, const int* in_sizes, int n_in,
                              void* d_out, int out_size, void* d_ws, size_t ws_size,
                              hipStream_t stream) {
  (void)n_in; (void)out_size; (void)d_ws; (void)ws_size;
  const float* x    = (const float*)d_in[0];
  const float* eWih = (const float*)d_in[1];
  const float* eWhh = (const float*)d_in[2];
  const float* ebih = (const float*)d_in[3];
  const float* ebhh = (const float*)d_in[4];
  const float* dWih = (const float*)d_in[5];
  const float* dWhh = (const float*)d_in[6];
  const float* dbih = (const float*)d_in[7];
  const float* dbhh = (const float*)d_in[8];
  const float* linW = (const float*)d_in[9];
  const float* linb = (const float*)d_in[10];

  const int B = in_sizes[0] / 40;          // [B][20][2]
  const int grid = (B + 31) / 32;          // 32 batch elems per block (2 tiles)
  lstm_fused<<<grid, 256, 0, stream>>>(x, eWih, eWhh, ebih, ebhh,
                                       dWih, dWhh, dbih, dbhh, linW, linb,
                                       (float*)d_out, B);
}